// Round 4
// baseline (285.929 us; speedup 1.0000x reference)
//
#include <hip/hip_runtime.h>
#include <hip/hip_bf16.h>
#include <cstdint>

// ---------------------------------------------------------------------------
// HierDSFeedForward: LN -> shared SwiGLU FFN + hierarchical top-2 MoE
// S=8192 tokens, C=512, H=1024, G=2 groups x EG=4 experts, K=2
// R3: gemm2_moe K-split=2 (grid 800->1600 blocks; occupancy was the binding
//     constraint at MfmaUtil 11%) + n-tile-major dispatch for A-gather reuse.
// ---------------------------------------------------------------------------

typedef __bf16 bf16x8 __attribute__((ext_vector_type(8)));
typedef __bf16 bf16x4 __attribute__((ext_vector_type(4)));
typedef float  f32x4  __attribute__((ext_vector_type(4)));

#define S_TOT 8192
#define C_DIM 512
#define H_DIM 1024
// max expert M-tiles: sum_e ceil(cnt_e/128) <= 16384/128 + 8 = 136
#define MAX_ETILES 136

// async global->LDS, 16B per lane. Per-lane GLOBAL address may scatter;
// LDS dest is wave-uniform base + lane*16.
__device__ __forceinline__ void gload_lds16(const void* g, void* l) {
  __builtin_amdgcn_global_load_lds(
      (__attribute__((address_space(1))) void*)(void*)(g),
      (__attribute__((address_space(3))) void*)(l),
      16, 0, 0);
}

// ---------------------------------------------------------------------------
// fused fp32 -> bf16 conversion for all weights, 4 elems/thread.
// dst layout: w1 = [siw(1M) | eiw(1M)], w2 = [eow(4M) | sow(0.5M)]
__global__ __launch_bounds__(256) void cvt_fused(
    const float* __restrict__ siw, const float* __restrict__ eiw,
    const float* __restrict__ eow, const float* __restrict__ sow,
    __bf16* __restrict__ w1, __bf16* __restrict__ w2) {
  const int i = (blockIdx.x * 256 + threadIdx.x) * 4;
  const float* src;
  __bf16* dst;
  if (i < 2097152) {  // w1
    src = (i < 1048576) ? (siw + i) : (eiw + (i - 1048576));
    dst = w1 + i;
  } else {            // w2
    const int j = i - 2097152;
    src = (j < 4194304) ? (eow + j) : (sow + (j - 4194304));
    dst = w2 + j;
  }
  float4 v = *(const float4*)src;
  bf16x4 o;
  o[0] = (__bf16)v.x; o[1] = (__bf16)v.y; o[2] = (__bf16)v.z; o[3] = (__bf16)v.w;
  *(bf16x4*)dst = o;
}

// ---------------------------------------------------------------------------
// Wave-per-token LayerNorm + hierarchical gating + output bias init.
// 4 tokens per 256-thread block; each lane owns 8 contiguous channels.
__global__ __launch_bounds__(256) void ln_gate_wave(
    const float* __restrict__ x,
    const float* __restrict__ ln_scale, const float* __restrict__ ln_bias,
    const float* __restrict__ ggw,   // [2,512]
    const float* __restrict__ egw,   // [8,512]
    const float* __restrict__ gb,    // [2]
    const float* __restrict__ eb,    // [8]
    const float* __restrict__ sob,   // [512]
    const float* __restrict__ eob,   // [8,512]
    __bf16* __restrict__ lnb,        // [8192,512] bf16 LN output
    float* __restrict__ comb,        // [8192,8] dense top-2 weights
    float* __restrict__ out)         // [8192,512] init: biases
{
  const int wave = threadIdx.x >> 6, lane = threadIdx.x & 63;
  const int s = blockIdx.x * 4 + wave;
  const size_t rowb = (size_t)s * C_DIM;
  const int c0 = lane * 8;

  const float4 va = *(const float4*)(x + rowb + c0);
  const float4 vb = *(const float4*)(x + rowb + c0 + 4);
  float v[8] = {va.x, va.y, va.z, va.w, vb.x, vb.y, vb.z, vb.w};

  // mean
  float sum = 0.f;
#pragma unroll
  for (int j = 0; j < 8; j++) sum += v[j];
#pragma unroll
  for (int o = 1; o < 64; o <<= 1) sum += __shfl_xor(sum, o, 64);
  const float mu = sum * (1.0f / 512.0f);

  // var
  float sq = 0.f;
#pragma unroll
  for (int j = 0; j < 8; j++) { const float d = v[j] - mu; sq += d * d; }
#pragma unroll
  for (int o = 1; o < 64; o <<= 1) sq += __shfl_xor(sq, o, 64);
  const float rs = rsqrtf(sq * (1.0f / 512.0f) + 1e-5f);

  const float4 sa = *(const float4*)(ln_scale + c0);
  const float4 sb = *(const float4*)(ln_scale + c0 + 4);
  const float4 ba = *(const float4*)(ln_bias + c0);
  const float4 bb = *(const float4*)(ln_bias + c0 + 4);
  const float sc[8] = {sa.x, sa.y, sa.z, sa.w, sb.x, sb.y, sb.z, sb.w};
  const float bi[8] = {ba.x, ba.y, ba.z, ba.w, bb.x, bb.y, bb.z, bb.w};

  float y[8];
  bf16x8 yb;
#pragma unroll
  for (int j = 0; j < 8; j++) {
    y[j] = (v[j] - mu) * rs * sc[j] + bi[j];
    yb[j] = (__bf16)y[j];
  }
  *(bf16x8*)(lnb + rowb + c0) = yb;

  // 10 gate dots (2 group + 8 expert) in fp64; per-lane partial over 8.
  double lg[10];
#pragma unroll
  for (int r = 0; r < 10; r++) {
    const float* W = (r < 2) ? (ggw + r * C_DIM + c0) : (egw + (r - 2) * C_DIM + c0);
    const float4 wa = *(const float4*)(W);
    const float4 wb = *(const float4*)(W + 4);
    const float w[8] = {wa.x, wa.y, wa.z, wa.w, wb.x, wb.y, wb.z, wb.w};
    double p = 0.0;
#pragma unroll
    for (int j = 0; j < 8; j++) p += (double)y[j] * (double)w[j];
    lg[r] = p;
  }
  // stage-outer so the 10 independent chains pipeline
#pragma unroll
  for (int o = 1; o < 64; o <<= 1) {
#pragma unroll
    for (int r = 0; r < 10; r++) lg[r] += __shfl_xor(lg[r], o, 64);
  }

  // routing — wave-uniform (every lane computes the same result)
  const double g0 = lg[0] + (double)gb[0], g1 = lg[1] + (double)gb[1];
  const int g = (g1 > g0) ? 1 : 0;  // argmax, first index wins ties
  double el[4], mx = -1e300;
#pragma unroll
  for (int j = 0; j < 4; j++) {
    el[j] = lg[2 + g * 4 + j] + (double)eb[g * 4 + j];
    if (el[j] > mx) mx = el[j];
  }
  double pr[4], ps = 0.0;
#pragma unroll
  for (int j = 0; j < 4; j++) { pr[j] = exp(el[j] - mx); ps += pr[j]; }
  int i0 = 0;
#pragma unroll
  for (int j = 1; j < 4; j++) if (pr[j] > pr[i0]) i0 = j;
  int i1 = -1;
#pragma unroll
  for (int j = 0; j < 4; j++) {
    if (j == i0) continue;
    if (i1 < 0 || pr[j] > pr[i1]) i1 = j;
  }
  const double p0 = pr[i0] / ps, p1 = pr[i1] / ps;
  const double nrm = p0 + p1 + 1e-8;
  const int e0 = g * 4 + i0, e1 = g * 4 + i1;
  const float w0 = (float)(p0 / nrm), w1 = (float)(p1 / nrm);

  if (lane < 8)
    comb[(size_t)s * 8 + lane] = (lane == e0) ? w0 : ((lane == e1) ? w1 : 0.0f);

  // out init: shared bias + the two selected experts' biases
  const float* eb0 = eob + e0 * C_DIM + c0;
  const float* eb1 = eob + e1 * C_DIM + c0;
  float4 oa, ob;
  {
    const float4 za = *(const float4*)(sob + c0);
    const float4 zb = *(const float4*)(sob + c0 + 4);
    const float4 ea = *(const float4*)(eb0);
    const float4 ebv = *(const float4*)(eb0 + 4);
    const float4 fa = *(const float4*)(eb1);
    const float4 fb = *(const float4*)(eb1 + 4);
    oa.x = za.x + ea.x + fa.x; oa.y = za.y + ea.y + fa.y;
    oa.z = za.z + ea.z + fa.z; oa.w = za.w + ea.w + fa.w;
    ob.x = zb.x + ebv.x + fb.x; ob.y = zb.y + ebv.y + fb.y;
    ob.z = zb.z + ebv.z + fb.z; ob.w = zb.w + ebv.w + fb.w;
  }
  *(float4*)(out + rowb + c0) = oa;
  *(float4*)(out + rowb + c0 + 4) = ob;
}

// ---------------------------------------------------------------------------
// Expert-list build, block-aggregated: 32 blocks x 256 tokens. Selections
// are re-derived from comb's nonzero entries. 8 global atomics per block.
__global__ __launch_bounds__(256) void build_lists(
    const float* __restrict__ comb, int* __restrict__ cnt,
    int* __restrict__ tok) {
  __shared__ int lcnt[8], lbase[8];
  const int t = threadIdx.x;
  if (t < 8) lcnt[t] = 0;
  __syncthreads();
  const int s = blockIdx.x * 256 + t;
  const float* cr = comb + (size_t)s * 8;
  int e0 = -1, e1 = -1;
#pragma unroll
  for (int j = 0; j < 8; j++) {
    if (cr[j] != 0.0f) { if (e0 < 0) e0 = j; else e1 = j; }
  }
  const int l0 = atomicAdd(&lcnt[e0], 1);
  const int l1 = (e1 >= 0) ? atomicAdd(&lcnt[e1], 1) : 0;
  __syncthreads();
  if (t < 8) lbase[t] = atomicAdd(&cnt[t], lcnt[t]);
  __syncthreads();
  tok[e0 * S_TOT + lbase[e0] + l0] = s;
  if (e1 >= 0) tok[e1 * S_TOT + lbase[e1] + l1] = s;
}

// ---------------------------------------------------------------------------
// tile prefix: off[e] = sum_{e'<e} ceil(cnt[e']/128); off[8] = total
__global__ void prefix_tiles(const int* __restrict__ cnt, int* __restrict__ off) {
  int s = 0;
#pragma unroll
  for (int e = 0; e < 8; e++) { off[e] = s; s += (cnt[e] + 127) >> 7; }
  off[8] = s;
}

// ---------------------------------------------------------------------------
// GEMM1 + fused SwiGLU. A = ln_bf16 [8192,512]; W1 = [4096,512] (rows:
// 0..1023 shared-a, 1024..2047 shared-b, 2048..3071 expert-a, 3072..4095
// expert-b). Block computes 128(M) x 64(N-of-h) via two B tiles in one
// K-loop, writes silu(a)*b to H [8192,2048] bf16
// (cols 0..1023 = h_shared, 1024..2047 = h_expert).
__global__ __launch_bounds__(256) void gemm1_swiglu(
    const __bf16* __restrict__ A,
    const __bf16* __restrict__ W1,
    __bf16* __restrict__ H)
{
  constexpr int K = C_DIM;  // 512
  __shared__ __bf16 As[128 * 32];
  __shared__ __bf16 Bas[64 * 32];
  __shared__ __bf16 Bbs[64 * 32];

  const int m0 = blockIdx.x * 128;
  const int nh = blockIdx.y * 64;
  const int arow0 = nh + (nh < 1024 ? 0 : 1024);
  const int brow0 = arow0 + 1024;

  const int tid = threadIdx.x, wave = tid >> 6, lane = tid & 63;
  const int wrow = wave >> 1, wcol = wave & 1;
  const int lr16 = lane >> 2;         // staging row-in-16
  const int lc   = (lane & 3) * 8;    // staging col elems
  const int fm   = lane & 15;         // fragment m/n
  const int fq   = (lane >> 4) * 8;   // fragment k base

  f32x4 acca[4][2] = {};
  f32x4 accb[4][2] = {};

  for (int k0 = 0; k0 < K; k0 += 32) {
#pragma unroll
    for (int i = 0; i < 2; i++) {
      const int rb = wave * 2 + i;
      gload_lds16(A + (size_t)(m0 + rb * 16 + lr16) * K + k0 + lc, As + rb * 512);
    }
    gload_lds16(W1 + (size_t)(arow0 + wave * 16 + lr16) * K + k0 + lc, Bas + wave * 512);
    gload_lds16(W1 + (size_t)(brow0 + wave * 16 + lr16) * K + k0 + lc, Bbs + wave * 512);
    __syncthreads();

    bf16x8 af[4], ba[2], bb[2];
#pragma unroll
    for (int mi = 0; mi < 4; mi++)
      af[mi] = *(const bf16x8*)&As[(wrow * 64 + mi * 16 + fm) * 32 + fq];
#pragma unroll
    for (int ni = 0; ni < 2; ni++) {
      const int r = wcol * 32 + ni * 16 + fm;
      ba[ni] = *(const bf16x8*)&Bas[r * 32 + fq];
      bb[ni] = *(const bf16x8*)&Bbs[r * 32 + fq];
    }
#pragma unroll
    for (int mi = 0; mi < 4; mi++) {
#pragma unroll
      for (int ni = 0; ni < 2; ni++) {
        acca[mi][ni] = __builtin_amdgcn_mfma_f32_16x16x32_bf16(af[mi], ba[ni], acca[mi][ni], 0, 0, 0);
        accb[mi][ni] = __builtin_amdgcn_mfma_f32_16x16x32_bf16(af[mi], bb[ni], accb[mi][ni], 0, 0, 0);
      }
    }
    __syncthreads();
  }

  // epilogue: silu(a) * b -> bf16
#pragma unroll
  for (int mi = 0; mi < 4; mi++) {
    const int row0 = m0 + wrow * 64 + mi * 16 + ((lane >> 4) << 2);
#pragma unroll
    for (int ni = 0; ni < 2; ni++) {
      const int c = nh + wcol * 32 + ni * 16 + fm;
#pragma unroll
      for (int r = 0; r < 4; r++) {
        const float a = acca[mi][ni][r];
        const float b = accb[mi][ni][r];
        const float sv = a / (1.0f + __expf(-a));
        H[(size_t)(row0 + r) * (2 * H_DIM) + c] = (__bf16)(sv * b);
      }
    }
  }
}

// ---------------------------------------------------------------------------
// Unified GEMM2 over compacted expert tiles + dense shared tiles.
// K-split=2 (blockIdx.z selects K half); n-tile on blockIdx.x (fastest) so
// the 4 consecutive blocks share one gathered A tile (L2/L3 reuse).
// blockIdx.y in [0, off[8])        : expert tiles, gathered A rows
// blockIdx.y in [off[8], off[8]+64): shared tiles, identity rows
// Epilogue: atomicAdd(out[token]) (out pre-init with biases).
__global__ __launch_bounds__(256) void gemm2_moe(
    const __bf16* __restrict__ Hb,   // [8192, 2048]
    const __bf16* __restrict__ W2,   // [9, 512, 1024] (8 experts + shared)
    const float* __restrict__ comb,  // [8192, 8]
    const int* __restrict__ cnt,     // [8]
    const int* __restrict__ tok,     // [8, 8192]
    const int* __restrict__ off,     // [9]
    float* __restrict__ out)         // [8192, 512]
{
  constexpr int K = H_DIM;   // 1024 (full row stride)
  constexpr int KS = 512;    // per-block K range (K-split=2)
  __shared__ __bf16 As[128 * 32];
  __shared__ __bf16 Bs[128 * 32];
  __shared__ int tokLDS[128];

  const int g = blockIdx.y;
  const int T = off[8];
  int e, m0;
  if (g < T) {
    e = 0;
    while (e < 7 && g >= off[e + 1]) e++;
    m0 = (g - off[e]) * 128;
  } else if (g < T + 64) {
    e = 8;
    m0 = (g - T) * 128;
  } else {
    return;
  }
  const int cnt_e = (e == 8) ? S_TOT : cnt[e];
  const int n0 = blockIdx.x * 128;
  const int kb = blockIdx.z * KS;
  const __bf16* Bw = W2 + (size_t)e * C_DIM * H_DIM + kb;
  const int abase = ((e == 8) ? 0 : H_DIM) + kb;

  const int tid = threadIdx.x, wave = tid >> 6, lane = tid & 63;
  const int wrow = wave >> 1, wcol = wave & 1;
  const int lr16 = lane >> 2;
  const int lc   = (lane & 3) * 8;
  const int fm   = lane & 15;
  const int fq   = (lane >> 4) * 8;

  if (tid < 128) {
    const int r = m0 + tid;
    tokLDS[tid] = (e == 8) ? r : ((r < cnt_e) ? tok[e * S_TOT + r] : -1);
  }
  __syncthreads();

  // per-lane gathered A base addresses (row fixed across K-loop)
  const int row0 = (wave * 2) * 16 + lr16;
  const int t0 = tokLDS[row0], t1 = tokLDS[row0 + 16];
  const __bf16* a0 = Hb + abase + (size_t)(t0 < 0 ? 0 : t0) * (2 * H_DIM) + lc;
  const __bf16* a1 = Hb + abase + (size_t)(t1 < 0 ? 0 : t1) * (2 * H_DIM) + lc;

  f32x4 acc[4][4] = {};

  for (int k0 = 0; k0 < KS; k0 += 32) {
    gload_lds16(a0 + k0, As + (wave * 2 + 0) * 512);
    gload_lds16(a1 + k0, As + (wave * 2 + 1) * 512);
#pragma unroll
    for (int i = 0; i < 2; i++) {
      const int rb = wave * 2 + i;
      gload_lds16(Bw + (size_t)(n0 + rb * 16 + lr16) * K + k0 + lc, Bs + rb * 512);
    }
    __syncthreads();

    bf16x8 af[4], bf[4];
#pragma unroll
    for (int mi = 0; mi < 4; mi++)
      af[mi] = *(const bf16x8*)&As[(wrow * 64 + mi * 16 + fm) * 32 + fq];
#pragma unroll
    for (int ni = 0; ni < 4; ni++)
      bf[ni] = *(const bf16x8*)&Bs[(wcol * 64 + ni * 16 + fm) * 32 + fq];
#pragma unroll
    for (int mi = 0; mi < 4; mi++)
#pragma unroll
      for (int ni = 0; ni < 4; ni++)
        acc[mi][ni] = __builtin_amdgcn_mfma_f32_16x16x32_bf16(af[mi], bf[ni], acc[mi][ni], 0, 0, 0);
    __syncthreads();
  }

#pragma unroll
  for (int mi = 0; mi < 4; mi++) {
    const int rbase = wrow * 64 + mi * 16 + ((lane >> 4) << 2);
#pragma unroll
    for (int r = 0; r < 4; r++) {
      const int token = tokLDS[rbase + r];
      if (token >= 0) {
        const float scale = (e == 8) ? 1.0f : comb[(size_t)token * 8 + e];
#pragma unroll
        for (int ni = 0; ni < 4; ni++) {
          const int c = n0 + wcol * 64 + ni * 16 + fm;
          atomicAdd(&out[(size_t)token * C_DIM + c], scale * acc[mi][ni][r]);
        }
      }
    }
  }
}

// ---------------------------------------------------------------------------
extern "C" void kernel_launch(void* const* d_in, const int* in_sizes, int n_in,
                              void* d_out, int out_size, void* d_ws, size_t ws_size,
                              hipStream_t stream) {
  const float* x    = (const float*)d_in[0];
  const float* lns  = (const float*)d_in[1];
  const float* lnbi = (const float*)d_in[2];
  const float* siw  = (const float*)d_in[3];   // [2048,512]
  const float* sow  = (const float*)d_in[4];   // [512,1024]
  const float* sob  = (const float*)d_in[5];   // [512]
  const float* eiw  = (const float*)d_in[6];   // [2048,512]
  const float* eow  = (const float*)d_in[7];   // [8,512,1024]
  const float* eob  = (const float*)d_in[8];   // [8,512]
  const float* ggw  = (const float*)d_in[9];   // [2,512]
  const float* egw  = (const float*)d_in[10];  // [8,512]
  const float* gb   = (const float*)d_in[11];  // [2]
  const float* eb   = (const float*)d_in[12];  // [8]
  float* out = (float*)d_out;

  // workspace layout (bytes)
  char* ws = (char*)d_ws;
  __bf16* w1   = (__bf16*)(ws);                 //  4,194,304  [4096,512]
  __bf16* w2   = (__bf16*)(ws + 4194304);       //  9,437,184  [9,512,1024]
  __bf16* lnb  = (__bf16*)(ws + 13631488);      //  8,388,608  [8192,512]
  __bf16* Hbuf = (__bf16*)(ws + 22020096);      // 33,554,432  [8192,2048]
  float*  comb = (float*)(ws + 55574528);       //    262,144  [8192,8]
  int*    tok  = (int*)(ws + 55836672);         //    262,144  [8,8192]
  int*    cnt  = (int*)(ws + 56098816);         //         32  [8]
  int*    off  = (int*)(ws + 56098848);         //         64  [9]
  // total: 56,098,912 bytes

  hipMemsetAsync(cnt, 0, 32, stream);

  // 1) weight conversion fp32->bf16 (single fused launch)
  cvt_fused<<<6656, 256, 0, stream>>>(siw, eiw, eow, sow, w1, w2);

  // 2) LayerNorm + gating + bias init (wave per token, 4 tokens/block)
  ln_gate_wave<<<S_TOT / 4, 256, 0, stream>>>(x, lns, lnbi, ggw, egw, gb, eb,
                                              sob, eob, lnb, comb, out);

  // 3) expert lists (block-aggregated atomics) + tile prefix
  build_lists<<<S_TOT / 256, 256, 0, stream>>>(comb, cnt, tok);
  prefix_tiles<<<1, 1, 0, stream>>>(cnt, off);

  // 4) GEMM1 + SwiGLU -> H [8192,2048] bf16
  gemm1_swiglu<<<dim3(S_TOT / 128, 2 * H_DIM / 64), 256, 0, stream>>>(lnb, w1, Hbuf);

  // 5) compacted GEMM2, K-split=2, n-tile-major for A reuse
  gemm2_moe<<<dim3(C_DIM / 128, MAX_ETILES + 64, 2), 256, 0, stream>>>(
      Hbuf, w2, comb, cnt, tok, off, out);
}

// Round 5
// 243.977 us; speedup vs baseline: 1.1720x; 1.1720x over previous
//
#include <hip/hip_runtime.h>
#include <hip/hip_bf16.h>
#include <cstdint>

// ---------------------------------------------------------------------------
// HierDSFeedForward: LN -> shared SwiGLU FFN + hierarchical top-2 MoE
// S=8192 tokens, C=512, H=1024, G=2 groups x EG=4 experts, K=2
// R4: revert R3's K-split (FETCH/WRITE regression, occupancy didn't move);
//     gemm2_moe BK=64 two-panel staging -> half the barrier drains, 2x MFMA
//     per drain. Panels kept at 64B row stride (flat 128B stride would be a
//     16-way bank conflict).
// ---------------------------------------------------------------------------

typedef __bf16 bf16x8 __attribute__((ext_vector_type(8)));
typedef __bf16 bf16x4 __attribute__((ext_vector_type(4)));
typedef float  f32x4  __attribute__((ext_vector_type(4)));

#define S_TOT 8192
#define C_DIM 512
#define H_DIM 1024
// max expert M-tiles: sum_e ceil(cnt_e/128) <= 16384/128 + 8 = 136
#define MAX_ETILES 136

// async global->LDS, 16B per lane. Per-lane GLOBAL address may scatter;
// LDS dest is wave-uniform base + lane*16.
__device__ __forceinline__ void gload_lds16(const void* g, void* l) {
  __builtin_amdgcn_global_load_lds(
      (__attribute__((address_space(1))) void*)(void*)(g),
      (__attribute__((address_space(3))) void*)(l),
      16, 0, 0);
}

// ---------------------------------------------------------------------------
// fused fp32 -> bf16 conversion for all weights, 4 elems/thread.
// dst layout: w1 = [siw(1M) | eiw(1M)], w2 = [eow(4M) | sow(0.5M)]
__global__ __launch_bounds__(256) void cvt_fused(
    const float* __restrict__ siw, const float* __restrict__ eiw,
    const float* __restrict__ eow, const float* __restrict__ sow,
    __bf16* __restrict__ w1, __bf16* __restrict__ w2) {
  const int i = (blockIdx.x * 256 + threadIdx.x) * 4;
  const float* src;
  __bf16* dst;
  if (i < 2097152) {  // w1
    src = (i < 1048576) ? (siw + i) : (eiw + (i - 1048576));
    dst = w1 + i;
  } else {            // w2
    const int j = i - 2097152;
    src = (j < 4194304) ? (eow + j) : (sow + (j - 4194304));
    dst = w2 + j;
  }
  float4 v = *(const float4*)src;
  bf16x4 o;
  o[0] = (__bf16)v.x; o[1] = (__bf16)v.y; o[2] = (__bf16)v.z; o[3] = (__bf16)v.w;
  *(bf16x4*)dst = o;
}

// ---------------------------------------------------------------------------
// Wave-per-token LayerNorm + hierarchical gating + output bias init.
// 4 tokens per 256-thread block; each lane owns 8 contiguous channels.
__global__ __launch_bounds__(256) void ln_gate_wave(
    const float* __restrict__ x,
    const float* __restrict__ ln_scale, const float* __restrict__ ln_bias,
    const float* __restrict__ ggw,   // [2,512]
    const float* __restrict__ egw,   // [8,512]
    const float* __restrict__ gb,    // [2]
    const float* __restrict__ eb,    // [8]
    const float* __restrict__ sob,   // [512]
    const float* __restrict__ eob,   // [8,512]
    __bf16* __restrict__ lnb,        // [8192,512] bf16 LN output
    float* __restrict__ comb,        // [8192,8] dense top-2 weights
    float* __restrict__ out)         // [8192,512] init: biases
{
  const int wave = threadIdx.x >> 6, lane = threadIdx.x & 63;
  const int s = blockIdx.x * 4 + wave;
  const size_t rowb = (size_t)s * C_DIM;
  const int c0 = lane * 8;

  const float4 va = *(const float4*)(x + rowb + c0);
  const float4 vb = *(const float4*)(x + rowb + c0 + 4);
  float v[8] = {va.x, va.y, va.z, va.w, vb.x, vb.y, vb.z, vb.w};

  // mean
  float sum = 0.f;
#pragma unroll
  for (int j = 0; j < 8; j++) sum += v[j];
#pragma unroll
  for (int o = 1; o < 64; o <<= 1) sum += __shfl_xor(sum, o, 64);
  const float mu = sum * (1.0f / 512.0f);

  // var
  float sq = 0.f;
#pragma unroll
  for (int j = 0; j < 8; j++) { const float d = v[j] - mu; sq += d * d; }
#pragma unroll
  for (int o = 1; o < 64; o <<= 1) sq += __shfl_xor(sq, o, 64);
  const float rs = rsqrtf(sq * (1.0f / 512.0f) + 1e-5f);

  const float4 sa = *(const float4*)(ln_scale + c0);
  const float4 sb = *(const float4*)(ln_scale + c0 + 4);
  const float4 ba = *(const float4*)(ln_bias + c0);
  const float4 bb = *(const float4*)(ln_bias + c0 + 4);
  const float sc[8] = {sa.x, sa.y, sa.z, sa.w, sb.x, sb.y, sb.z, sb.w};
  const float bi[8] = {ba.x, ba.y, ba.z, ba.w, bb.x, bb.y, bb.z, bb.w};

  float y[8];
  bf16x8 yb;
#pragma unroll
  for (int j = 0; j < 8; j++) {
    y[j] = (v[j] - mu) * rs * sc[j] + bi[j];
    yb[j] = (__bf16)y[j];
  }
  *(bf16x8*)(lnb + rowb + c0) = yb;

  // 10 gate dots (2 group + 8 expert) in fp64; per-lane partial over 8.
  double lg[10];
#pragma unroll
  for (int r = 0; r < 10; r++) {
    const float* W = (r < 2) ? (ggw + r * C_DIM + c0) : (egw + (r - 2) * C_DIM + c0);
    const float4 wa = *(const float4*)(W);
    const float4 wb = *(const float4*)(W + 4);
    const float w[8] = {wa.x, wa.y, wa.z, wa.w, wb.x, wb.y, wb.z, wb.w};
    double p = 0.0;
#pragma unroll
    for (int j = 0; j < 8; j++) p += (double)y[j] * (double)w[j];
    lg[r] = p;
  }
  // stage-outer so the 10 independent chains pipeline
#pragma unroll
  for (int o = 1; o < 64; o <<= 1) {
#pragma unroll
    for (int r = 0; r < 10; r++) lg[r] += __shfl_xor(lg[r], o, 64);
  }

  // routing — wave-uniform (every lane computes the same result)
  const double g0 = lg[0] + (double)gb[0], g1 = lg[1] + (double)gb[1];
  const int g = (g1 > g0) ? 1 : 0;  // argmax, first index wins ties
  double el[4], mx = -1e300;
#pragma unroll
  for (int j = 0; j < 4; j++) {
    el[j] = lg[2 + g * 4 + j] + (double)eb[g * 4 + j];
    if (el[j] > mx) mx = el[j];
  }
  double pr[4], ps = 0.0;
#pragma unroll
  for (int j = 0; j < 4; j++) { pr[j] = exp(el[j] - mx); ps += pr[j]; }
  int i0 = 0;
#pragma unroll
  for (int j = 1; j < 4; j++) if (pr[j] > pr[i0]) i0 = j;
  int i1 = -1;
#pragma unroll
  for (int j = 0; j < 4; j++) {
    if (j == i0) continue;
    if (i1 < 0 || pr[j] > pr[i1]) i1 = j;
  }
  const double p0 = pr[i0] / ps, p1 = pr[i1] / ps;
  const double nrm = p0 + p1 + 1e-8;
  const int e0 = g * 4 + i0, e1 = g * 4 + i1;
  const float w0 = (float)(p0 / nrm), w1 = (float)(p1 / nrm);

  if (lane < 8)
    comb[(size_t)s * 8 + lane] = (lane == e0) ? w0 : ((lane == e1) ? w1 : 0.0f);

  // out init: shared bias + the two selected experts' biases
  const float* eb0 = eob + e0 * C_DIM + c0;
  const float* eb1 = eob + e1 * C_DIM + c0;
  float4 oa, ob;
  {
    const float4 za = *(const float4*)(sob + c0);
    const float4 zb = *(const float4*)(sob + c0 + 4);
    const float4 ea = *(const float4*)(eb0);
    const float4 ebv = *(const float4*)(eb0 + 4);
    const float4 fa = *(const float4*)(eb1);
    const float4 fb = *(const float4*)(eb1 + 4);
    oa.x = za.x + ea.x + fa.x; oa.y = za.y + ea.y + fa.y;
    oa.z = za.z + ea.z + fa.z; oa.w = za.w + ea.w + fa.w;
    ob.x = zb.x + ebv.x + fb.x; ob.y = zb.y + ebv.y + fb.y;
    ob.z = zb.z + ebv.z + fb.z; ob.w = zb.w + ebv.w + fb.w;
  }
  *(float4*)(out + rowb + c0) = oa;
  *(float4*)(out + rowb + c0 + 4) = ob;
}

// ---------------------------------------------------------------------------
// Expert-list build, block-aggregated: 32 blocks x 256 tokens. Selections
// are re-derived from comb's nonzero entries. 8 global atomics per block.
__global__ __launch_bounds__(256) void build_lists(
    const float* __restrict__ comb, int* __restrict__ cnt,
    int* __restrict__ tok) {
  __shared__ int lcnt[8], lbase[8];
  const int t = threadIdx.x;
  if (t < 8) lcnt[t] = 0;
  __syncthreads();
  const int s = blockIdx.x * 256 + t;
  const float* cr = comb + (size_t)s * 8;
  int e0 = -1, e1 = -1;
#pragma unroll
  for (int j = 0; j < 8; j++) {
    if (cr[j] != 0.0f) { if (e0 < 0) e0 = j; else e1 = j; }
  }
  const int l0 = atomicAdd(&lcnt[e0], 1);
  const int l1 = (e1 >= 0) ? atomicAdd(&lcnt[e1], 1) : 0;
  __syncthreads();
  if (t < 8) lbase[t] = atomicAdd(&cnt[t], lcnt[t]);
  __syncthreads();
  tok[e0 * S_TOT + lbase[e0] + l0] = s;
  if (e1 >= 0) tok[e1 * S_TOT + lbase[e1] + l1] = s;
}

// ---------------------------------------------------------------------------
// tile prefix: off[e] = sum_{e'<e} ceil(cnt[e']/128); off[8] = total
__global__ void prefix_tiles(const int* __restrict__ cnt, int* __restrict__ off) {
  int s = 0;
#pragma unroll
  for (int e = 0; e < 8; e++) { off[e] = s; s += (cnt[e] + 127) >> 7; }
  off[8] = s;
}

// ---------------------------------------------------------------------------
// GEMM1 + fused SwiGLU. A = ln_bf16 [8192,512]; W1 = [4096,512] (rows:
// 0..1023 shared-a, 1024..2047 shared-b, 2048..3071 expert-a, 3072..4095
// expert-b). Block computes 128(M) x 64(N-of-h) via two B tiles in one
// K-loop, writes silu(a)*b to H [8192,2048] bf16
// (cols 0..1023 = h_shared, 1024..2047 = h_expert).
__global__ __launch_bounds__(256) void gemm1_swiglu(
    const __bf16* __restrict__ A,
    const __bf16* __restrict__ W1,
    __bf16* __restrict__ H)
{
  constexpr int K = C_DIM;  // 512
  __shared__ __bf16 As[128 * 32];
  __shared__ __bf16 Bas[64 * 32];
  __shared__ __bf16 Bbs[64 * 32];

  const int m0 = blockIdx.x * 128;
  const int nh = blockIdx.y * 64;
  const int arow0 = nh + (nh < 1024 ? 0 : 1024);
  const int brow0 = arow0 + 1024;

  const int tid = threadIdx.x, wave = tid >> 6, lane = tid & 63;
  const int wrow = wave >> 1, wcol = wave & 1;
  const int lr16 = lane >> 2;         // staging row-in-16
  const int lc   = (lane & 3) * 8;    // staging col elems
  const int fm   = lane & 15;         // fragment m/n
  const int fq   = (lane >> 4) * 8;   // fragment k base

  f32x4 acca[4][2] = {};
  f32x4 accb[4][2] = {};

  for (int k0 = 0; k0 < K; k0 += 32) {
#pragma unroll
    for (int i = 0; i < 2; i++) {
      const int rb = wave * 2 + i;
      gload_lds16(A + (size_t)(m0 + rb * 16 + lr16) * K + k0 + lc, As + rb * 512);
    }
    gload_lds16(W1 + (size_t)(arow0 + wave * 16 + lr16) * K + k0 + lc, Bas + wave * 512);
    gload_lds16(W1 + (size_t)(brow0 + wave * 16 + lr16) * K + k0 + lc, Bbs + wave * 512);
    __syncthreads();

    bf16x8 af[4], ba[2], bb[2];
#pragma unroll
    for (int mi = 0; mi < 4; mi++)
      af[mi] = *(const bf16x8*)&As[(wrow * 64 + mi * 16 + fm) * 32 + fq];
#pragma unroll
    for (int ni = 0; ni < 2; ni++) {
      const int r = wcol * 32 + ni * 16 + fm;
      ba[ni] = *(const bf16x8*)&Bas[r * 32 + fq];
      bb[ni] = *(const bf16x8*)&Bbs[r * 32 + fq];
    }
#pragma unroll
    for (int mi = 0; mi < 4; mi++) {
#pragma unroll
      for (int ni = 0; ni < 2; ni++) {
        acca[mi][ni] = __builtin_amdgcn_mfma_f32_16x16x32_bf16(af[mi], ba[ni], acca[mi][ni], 0, 0, 0);
        accb[mi][ni] = __builtin_amdgcn_mfma_f32_16x16x32_bf16(af[mi], bb[ni], accb[mi][ni], 0, 0, 0);
      }
    }
    __syncthreads();
  }

  // epilogue: silu(a) * b -> bf16
#pragma unroll
  for (int mi = 0; mi < 4; mi++) {
    const int row0 = m0 + wrow * 64 + mi * 16 + ((lane >> 4) << 2);
#pragma unroll
    for (int ni = 0; ni < 2; ni++) {
      const int c = nh + wcol * 32 + ni * 16 + fm;
#pragma unroll
      for (int r = 0; r < 4; r++) {
        const float a = acca[mi][ni][r];
        const float b = accb[mi][ni][r];
        const float sv = a / (1.0f + __expf(-a));
        H[(size_t)(row0 + r) * (2 * H_DIM) + c] = (__bf16)(sv * b);
      }
    }
  }
}

// ---------------------------------------------------------------------------
// Unified GEMM2 over compacted expert tiles + dense shared tiles.
// BK=64 via two 32-wide K-panels per iteration: 16 barrier drains instead
// of 32, 32 MFMA per drain per wave. Each panel keeps the 64B row stride.
// blockIdx.x in [0, off[8])        : expert tiles, gathered A rows
// blockIdx.x in [off[8], off[8]+64): shared tiles, identity rows
// Epilogue: atomicAdd(out[token]) (out pre-init with biases).
__global__ __launch_bounds__(256) void gemm2_moe(
    const __bf16* __restrict__ Hb,   // [8192, 2048]
    const __bf16* __restrict__ W2,   // [9, 512, 1024] (8 experts + shared)
    const float* __restrict__ comb,  // [8192, 8]
    const int* __restrict__ cnt,     // [8]
    const int* __restrict__ tok,     // [8, 8192]
    const int* __restrict__ off,     // [9]
    float* __restrict__ out)         // [8192, 512]
{
  constexpr int K = H_DIM;  // 1024
  __shared__ __bf16 As[2 * 128 * 32];   // [panel][row][32]
  __shared__ __bf16 Bs[2 * 128 * 32];
  __shared__ int tokLDS[128];

  const int g = blockIdx.x;
  const int T = off[8];
  int e, m0;
  if (g < T) {
    e = 0;
    while (e < 7 && g >= off[e + 1]) e++;
    m0 = (g - off[e]) * 128;
  } else if (g < T + 64) {
    e = 8;
    m0 = (g - T) * 128;
  } else {
    return;
  }
  const int cnt_e = (e == 8) ? S_TOT : cnt[e];
  const int n0 = blockIdx.y * 128;
  const __bf16* Bw = W2 + (size_t)e * C_DIM * H_DIM;
  const int abase = (e == 8) ? 0 : H_DIM;

  const int tid = threadIdx.x, wave = tid >> 6, lane = tid & 63;
  const int wrow = wave >> 1, wcol = wave & 1;
  const int lr16 = lane >> 2;
  const int lc   = (lane & 3) * 8;
  const int fm   = lane & 15;
  const int fq   = (lane >> 4) * 8;

  if (tid < 128) {
    const int r = m0 + tid;
    tokLDS[tid] = (e == 8) ? r : ((r < cnt_e) ? tok[e * S_TOT + r] : -1);
  }
  __syncthreads();

  // per-lane gathered A base addresses (rows fixed across K-loop):
  // this wave stages A rows wave*32 + {0,16} + lr16 (both panels)
  const int row0 = wave * 32 + lr16;
  const int t0 = tokLDS[row0], t1 = tokLDS[row0 + 16];
  const __bf16* a0 = Hb + abase + (size_t)(t0 < 0 ? 0 : t0) * (2 * H_DIM) + lc;
  const __bf16* a1 = Hb + abase + (size_t)(t1 < 0 ? 0 : t1) * (2 * H_DIM) + lc;
  const __bf16* b0 = Bw + (size_t)(n0 + wave * 32 + lr16) * K + lc;
  const __bf16* b1 = Bw + (size_t)(n0 + wave * 32 + 16 + lr16) * K + lc;

  // LDS staging bases (elements) for this wave
  const int sA0 = (wave * 32) * 32;        // panel offset += 4096
  const int sA1 = (wave * 32 + 16) * 32;

  f32x4 acc[4][4] = {};

  for (int k0 = 0; k0 < K; k0 += 64) {
    // panel 0: cols k0..k0+31, panel 1: cols k0+32..k0+63
    gload_lds16(a0 + k0,      As + sA0);
    gload_lds16(a0 + k0 + 32, As + 4096 + sA0);
    gload_lds16(a1 + k0,      As + sA1);
    gload_lds16(a1 + k0 + 32, As + 4096 + sA1);
    gload_lds16(b0 + k0,      Bs + sA0);
    gload_lds16(b0 + k0 + 32, Bs + 4096 + sA0);
    gload_lds16(b1 + k0,      Bs + sA1);
    gload_lds16(b1 + k0 + 32, Bs + 4096 + sA1);
    __syncthreads();

#pragma unroll
    for (int kc = 0; kc < 2; kc++) {
      bf16x8 af[4], bf[4];
#pragma unroll
      for (int mi = 0; mi < 4; mi++)
        af[mi] = *(const bf16x8*)&As[kc * 4096 + (wrow * 64 + mi * 16 + fm) * 32 + fq];
#pragma unroll
      for (int ni = 0; ni < 4; ni++)
        bf[ni] = *(const bf16x8*)&Bs[kc * 4096 + (wcol * 64 + ni * 16 + fm) * 32 + fq];
#pragma unroll
      for (int mi = 0; mi < 4; mi++)
#pragma unroll
        for (int ni = 0; ni < 4; ni++)
          acc[mi][ni] = __builtin_amdgcn_mfma_f32_16x16x32_bf16(af[mi], bf[ni], acc[mi][ni], 0, 0, 0);
    }
    __syncthreads();
  }

#pragma unroll
  for (int mi = 0; mi < 4; mi++) {
    const int rbase = wrow * 64 + mi * 16 + ((lane >> 4) << 2);
#pragma unroll
    for (int r = 0; r < 4; r++) {
      const int token = tokLDS[rbase + r];
      if (token >= 0) {
        const float scale = (e == 8) ? 1.0f : comb[(size_t)token * 8 + e];
#pragma unroll
        for (int ni = 0; ni < 4; ni++) {
          const int c = n0 + wcol * 64 + ni * 16 + fm;
          atomicAdd(&out[(size_t)token * C_DIM + c], scale * acc[mi][ni][r]);
        }
      }
    }
  }
}

// ---------------------------------------------------------------------------
extern "C" void kernel_launch(void* const* d_in, const int* in_sizes, int n_in,
                              void* d_out, int out_size, void* d_ws, size_t ws_size,
                              hipStream_t stream) {
  const float* x    = (const float*)d_in[0];
  const float* lns  = (const float*)d_in[1];
  const float* lnbi = (const float*)d_in[2];
  const float* siw  = (const float*)d_in[3];   // [2048,512]
  const float* sow  = (const float*)d_in[4];   // [512,1024]
  const float* sob  = (const float*)d_in[5];   // [512]
  const float* eiw  = (const float*)d_in[6];   // [2048,512]
  const float* eow  = (const float*)d_in[7];   // [8,512,1024]
  const float* eob  = (const float*)d_in[8];   // [8,512]
  const float* ggw  = (const float*)d_in[9];   // [2,512]
  const float* egw  = (const float*)d_in[10];  // [8,512]
  const float* gb   = (const float*)d_in[11];  // [2]
  const float* eb   = (const float*)d_in[12];  // [8]
  float* out = (float*)d_out;

  // workspace layout (bytes)
  char* ws = (char*)d_ws;
  __bf16* w1   = (__bf16*)(ws);                 //  4,194,304  [4096,512]
  __bf16* w2   = (__bf16*)(ws + 4194304);       //  9,437,184  [9,512,1024]
  __bf16* lnb  = (__bf16*)(ws + 13631488);      //  8,388,608  [8192,512]
  __bf16* Hbuf = (__bf16*)(ws + 22020096);      // 33,554,432  [8192,2048]
  float*  comb = (float*)(ws + 55574528);       //    262,144  [8192,8]
  int*    tok  = (int*)(ws + 55836672);         //    262,144  [8,8192]
  int*    cnt  = (int*)(ws + 56098816);         //         32  [8]
  int*    off  = (int*)(ws + 56098848);         //         64  [9]
  // total: 56,098,912 bytes

  hipMemsetAsync(cnt, 0, 32, stream);

  // 1) weight conversion fp32->bf16 (single fused launch)
  cvt_fused<<<6656, 256, 0, stream>>>(siw, eiw, eow, sow, w1, w2);

  // 2) LayerNorm + gating + bias init (wave per token, 4 tokens/block)
  ln_gate_wave<<<S_TOT / 4, 256, 0, stream>>>(x, lns, lnbi, ggw, egw, gb, eb,
                                              sob, eob, lnb, comb, out);

  // 3) expert lists (block-aggregated atomics) + tile prefix
  build_lists<<<S_TOT / 256, 256, 0, stream>>>(comb, cnt, tok);
  prefix_tiles<<<1, 1, 0, stream>>>(cnt, off);

  // 4) GEMM1 + SwiGLU -> H [8192,2048] bf16
  gemm1_swiglu<<<dim3(S_TOT / 128, 2 * H_DIM / 64), 256, 0, stream>>>(lnb, w1, Hbuf);

  // 5) compacted GEMM2 (BK=64, R2 dispatch order)
  gemm2_moe<<<dim3(MAX_ETILES + 64, C_DIM / 128), 256, 0, stream>>>(
      Hbuf, w2, comb, cnt, tok, off, out);
}